// Round 1
// baseline (230.747 us; speedup 1.0000x reference)
//
#include <hip/hip_runtime.h>
#include <hip/hip_bf16.h>
#include <stdint.h>

#define B_    4
#define N_    4096
#define FIN   64
#define NPROP 64
#define NFILT 128
#define KSEL  40
#define ROWS  (B_ * N_)

// ---------------- K1: features = x@W_flr + b_flr ; coords = x@W_s + b_s ----
__global__ __launch_bounds__(256) void k1_proj(
    const float* __restrict__ x, const float* __restrict__ Wf, const float* __restrict__ bf,
    const float* __restrict__ Ws, const float* __restrict__ bs,
    float* __restrict__ feat, float4* __restrict__ coords)
{
    int wid  = threadIdx.x >> 6;
    int lane = threadIdx.x & 63;
    int row  = blockIdx.x * 4 + wid;

    float xv = x[row * FIN + lane];          // lane holds x[row][lane]
    float acc = bf[lane];
    float c0 = bs[0], c1 = bs[1], c2 = bs[2], c3 = bs[3];
    #pragma unroll 16
    for (int k = 0; k < FIN; ++k) {
        float xk = __shfl(xv, k);
        acc += xk * Wf[k * NPROP + lane];
        float4 w4 = reinterpret_cast<const float4*>(Ws)[k];
        c0 += xk * w4.x; c1 += xk * w4.y; c2 += xk * w4.z; c3 += xk * w4.w;
    }
    feat[row * NPROP + lane] = acc;
    if (lane == 0) coords[row] = make_float4(c0, c1, c2, c3);
}

// ---------------- K2: KNN top-40 + weighted max/mean aggregation ----------
// One wave per query row. Block = 16 waves sharing the batch's coords in LDS.
// Selection: wave-wide sorted top-64 list, one 32-bit key per lane,
// key = (bits(dist) & ~0xFFF) | j  (monotone in (dist, j), matches jax tie-break).
__global__ __launch_bounds__(1024) void k2_knn(
    const float4* __restrict__ coords, const float* __restrict__ feat,
    float* __restrict__ aggout)
{
    __shared__ float4 cl[N_];                 // 64 KB
    int tid  = threadIdx.x;
    int row0 = blockIdx.x * 16;
    int b    = row0 >> 12;                    // N_=4096 rows per batch
    const float4* cb = coords + (size_t)b * N_;
    for (int idx = tid; idx < N_; idx += 1024) cl[idx] = cb[idx];
    __syncthreads();

    int wid = tid >> 6, lane = tid & 63;
    int row = row0 + wid;
    int i   = row & (N_ - 1);

    float4 q = cl[i];
    float ni = q.x*q.x + q.y*q.y + q.z*q.z + q.w*q.w;

    unsigned R = 0xFFFFFFFFu;                 // sorted ascending across lanes
    for (int t = 0; t < 64; ++t) {
        int j = t * 64 + lane;
        float4 c = cl[j];
        float nj = c.x*c.x + c.y*c.y + c.z*c.z + c.w*c.w;
        float dt = q.x*c.x + q.y*c.y + q.z*c.z + q.w*c.w;
        float d  = fabsf(-2.0f * dt + ni + nj);        // exactly 0 for j==i
        unsigned key = (__float_as_uint(d) & 0xFFFFF000u) | (unsigned)j;

        unsigned r63 = __shfl(R, 63);                  // current 64th best
        unsigned long long m = __ballot(key < r63);    // wave-uniform mask
        while (m) {
            int src = __ffsll(m) - 1;
            m &= m - 1;
            unsigned xk   = __shfl(key, src);          // broadcast candidate
            unsigned prev = __shfl_up(R, 1);
            if (lane == 0) prev = 0u;
            unsigned cand = prev > xk ? prev : xk;
            R = (R <= xk) ? R : cand;                  // sorted insert, drop max
        }
    }

    // lanes 0..39 of R hold top-40 (lane 0 = self). Aggregate lanes 1..39.
    float mx = -3.4e38f, sm = 0.0f;
    const float* fb = feat + (size_t)b * N_ * NPROP;
    for (int s = 1; s < KSEL; ++s) {
        unsigned ks = __shfl(R, s);
        int j = (int)(ks & 0xFFFu);
        float4 c = cl[j];
        float nj = c.x*c.x + c.y*c.y + c.z*c.z + c.w*c.w;
        float dt = q.x*c.x + q.y*c.y + q.z*c.z + q.w*c.w;
        float d  = fabsf(-2.0f * dt + ni + nj);        // exact dist for weight
        float w  = __expf(-10.0f * d);
        float f  = fb[(size_t)j * NPROP + lane];       // coalesced 256B row
        float wf = w * f;
        mx = fmaxf(mx, wf);
        sm += wf;
    }
    aggout[(size_t)row * NFILT + lane]      = mx;
    aggout[(size_t)row * NFILT + 64 + lane] = sm * (1.0f / 39.0f);
}

// ---------------- K3: out = [x | max | mean] @ W_out + b_out --------------
// In-place over d_out: agg rows staged to LDS before the block overwrites them.
__global__ __launch_bounds__(256) void k3_out(
    const float* __restrict__ x, const float* __restrict__ agg,
    const float* __restrict__ Wo, const float* __restrict__ bo,
    float* __restrict__ out)
{
    __shared__ float xa[64 * FIN];    // 16 KB
    __shared__ float ga[64 * NFILT];  // 32 KB
    int tid = threadIdx.x;
    int r0  = blockIdx.x * 64;
    for (int idx = tid; idx < 64 * FIN; idx += 256) {
        int r = idx >> 6, k = idx & 63;
        xa[idx] = x[(size_t)(r0 + r) * FIN + k];
    }
    for (int idx = tid; idx < 64 * NFILT; idx += 256) {
        int r = idx >> 7, k = idx & 127;
        ga[idx] = agg[(size_t)(r0 + r) * NFILT + k];
    }
    __syncthreads();

    int c = tid & 127, rh = tid >> 7;
    float acc[32];
    float bb = bo[c];
    #pragma unroll
    for (int rr = 0; rr < 32; ++rr) acc[rr] = bb;

    for (int k = 0; k < FIN; ++k) {
        float w = Wo[k * NFILT + c];
        #pragma unroll
        for (int rr = 0; rr < 32; ++rr)
            acc[rr] += xa[(rh * 32 + rr) * FIN + k] * w;     // LDS broadcast
    }
    for (int k = 0; k < NFILT; ++k) {
        float w = Wo[(FIN + k) * NFILT + c];
        #pragma unroll
        for (int rr = 0; rr < 32; ++rr)
            acc[rr] += ga[(rh * 32 + rr) * NFILT + k] * w;
    }
    #pragma unroll
    for (int rr = 0; rr < 32; ++rr)
        out[(size_t)(r0 + rh * 32 + rr) * NFILT + c] = acc[rr];
}

extern "C" void kernel_launch(void* const* d_in, const int* in_sizes, int n_in,
                              void* d_out, int out_size, void* d_ws, size_t ws_size,
                              hipStream_t stream)
{
    const float* x  = (const float*)d_in[0];
    const float* Wf = (const float*)d_in[1];
    const float* bf = (const float*)d_in[2];
    const float* Ws = (const float*)d_in[3];
    const float* bs = (const float*)d_in[4];
    const float* Wo = (const float*)d_in[5];
    const float* bo = (const float*)d_in[6];
    float* out = (float*)d_out;

    float*  feat   = (float*)d_ws;                                        // 4 MB
    float4* coords = (float4*)((char*)d_ws + (size_t)ROWS * NPROP * 4);   // 256 KB

    k1_proj<<<ROWS / 4,  256,  0, stream>>>(x, Wf, bf, Ws, bs, feat, coords);
    k2_knn <<<ROWS / 16, 1024, 0, stream>>>(coords, feat, out);
    k3_out <<<ROWS / 64, 256,  0, stream>>>(x, out, Wo, bo, out);
}

// Round 2
// 157.465 us; speedup vs baseline: 1.4654x; 1.4654x over previous
//
#include <hip/hip_runtime.h>
#include <hip/hip_bf16.h>
#include <stdint.h>

#define B_    4
#define N_    4096
#define FIN   64
#define NPROP 64
#define NFILT 128
#define KSEL  40
#define ROWS  (B_ * N_)
#define M_    12            // per-lane top list size (overflow risk ~1e-7)

// ---------------- K1: features = x@W_flr + b_flr ; coords = x@W_s + b_s ----
__global__ __launch_bounds__(256) void k1_proj(
    const float* __restrict__ x, const float* __restrict__ Wf, const float* __restrict__ bf,
    const float* __restrict__ Ws, const float* __restrict__ bs,
    float* __restrict__ feat, float4* __restrict__ coords)
{
    int wid  = threadIdx.x >> 6;
    int lane = threadIdx.x & 63;
    int row  = blockIdx.x * 4 + wid;

    float xv = x[row * FIN + lane];
    float acc = bf[lane];
    float c0 = bs[0], c1 = bs[1], c2 = bs[2], c3 = bs[3];
    #pragma unroll 16
    for (int k = 0; k < FIN; ++k) {
        float xk = __shfl(xv, k);
        acc += xk * Wf[k * NPROP + lane];
        float4 w4 = reinterpret_cast<const float4*>(Ws)[k];
        c0 += xk * w4.x; c1 += xk * w4.y; c2 += xk * w4.z; c3 += xk * w4.w;
    }
    feat[row * NPROP + lane] = acc;
    if (lane == 0) coords[row] = make_float4(c0, c1, c2, c3);
}

// ---------------- K2: KNN top-40 + weighted max/mean aggregation ----------
// One wave per query. Lane L streams candidates j = L*64+t from a transposed,
// XOR-swizzled LDS copy (conflict-free ds_read_b128), keeping a PRIVATE
// register top-12 list (branch-free min/max bubble, no cross-lane serial
// chain). A 40-round tournament (6-step shfl_xor min over lane heads) then
// pops the exact global top-40 in (dist, idx)-lexicographic order.
__global__ __launch_bounds__(1024) void k2_knn(
    const float4* __restrict__ coords, const float* __restrict__ feat,
    float* __restrict__ aggout)
{
    __shared__ float4 cT[N_];   // 64 KB, transposed + swizzled
    __shared__ float  nT[N_];   // 16 KB, squared norms, same layout
    int tid  = threadIdx.x;
    int row0 = blockIdx.x * 16;
    int b    = row0 >> 12;
    const float4* cb = coords + (size_t)b * N_;

    for (int idx = tid; idx < N_; idx += 1024) {
        float4 c = cb[idx];
        float n = c.x * c.x; n = fmaf(c.y, c.y, n); n = fmaf(c.z, c.z, n); n = fmaf(c.w, c.w, n);
        int p  = ((idx & 63) << 6) | (idx >> 6);     // transpose
        int ps = p ^ ((p >> 6) & 63);                // XOR swizzle (bank-spread)
        cT[ps] = c; nT[ps] = n;
    }
    __syncthreads();

    int wid = tid >> 6, lane = tid & 63;
    int row = row0 + wid;
    int i   = row & (N_ - 1);

    int pi  = ((i & 63) << 6) | (i >> 6);
    int pis = pi ^ (i & 63);
    float4 q = cT[pis];          // uniform -> LDS broadcast
    float ni = nT[pis];

    unsigned l[M_];
    #pragma unroll
    for (int m = 0; m < M_; ++m) l[m] = 0xFFFFFFFFu;

    // candidate stream: lane handles j = lane*64 + t, stored at t*64+lane
    #pragma unroll 4
    for (int t = 0; t < 64; ++t) {
        int p  = t * 64 + lane;
        int ps = p ^ t;                              // (p>>6)&63 == t
        float4 c = cT[ps];
        float nj = nT[ps];
        float dt = q.x * c.x; dt = fmaf(q.y, c.y, dt); dt = fmaf(q.z, c.z, dt); dt = fmaf(q.w, c.w, dt);
        float s  = fmaf(dt, -2.0f, ni + nj);         // >=0; exactly 0 for self
        unsigned key = (__float_as_uint(s) & 0xFFFFF000u) | (unsigned)(lane * 64 + t);
        bool pr = key < l[M_ - 1];
        if (__any(pr)) {                             // wave-uniform gate
            unsigned cur = pr ? key : 0xFFFFFFFFu;   // MAX = no-op insert
            #pragma unroll
            for (int m = 0; m < M_; ++m) {
                unsigned lo = min(l[m], cur);
                unsigned hi = max(l[m], cur);
                l[m] = lo; cur = hi;
            }
        }
    }

    // tournament: pop global min 40 times (pop 0 = self, d==0 exactly)
    unsigned selk = 0xFFFFFFFFu;
    #pragma unroll 1
    for (int ks = 0; ks < KSEL; ++ks) {
        unsigned h = l[0];
        h = min(h, (unsigned)__shfl_xor((int)h, 1));
        h = min(h, (unsigned)__shfl_xor((int)h, 2));
        h = min(h, (unsigned)__shfl_xor((int)h, 4));
        h = min(h, (unsigned)__shfl_xor((int)h, 8));
        h = min(h, (unsigned)__shfl_xor((int)h, 16));
        h = min(h, (unsigned)__shfl_xor((int)h, 32));
        int j = (int)(h & 0xFFFu);
        bool own = (lane == (j >> 6));
        #pragma unroll
        for (int m = 0; m < M_ - 1; ++m) l[m] = own ? l[m + 1] : l[m];
        l[M_ - 1] = own ? 0xFFFFFFFFu : l[M_ - 1];
        if (lane == ks) selk = h;                    // record winner
    }

    // aggregation over pops 1..39 (independent loads -> pipelined)
    float mx = -3.4e38f, sm = 0.0f;
    const float* fb = feat + (size_t)b * N_ * NPROP;
    #pragma unroll 4
    for (int s = 1; s < KSEL; ++s) {
        unsigned h = (unsigned)__shfl((int)selk, s);
        int j  = (int)(h & 0xFFFu);
        int pj = ((j & 63) << 6) | (j >> 6);
        int pjs = pj ^ (j & 63);
        float4 c = cT[pjs];                          // uniform broadcast
        float nj = nT[pjs];
        float dt = q.x * c.x; dt = fmaf(q.y, c.y, dt); dt = fmaf(q.z, c.z, dt); dt = fmaf(q.w, c.w, dt);
        float d  = fabsf(fmaf(dt, -2.0f, ni + nj));
        float w  = __expf(-10.0f * d);
        float f  = fb[(size_t)j * NPROP + lane];
        float wf = w * f;
        mx = fmaxf(mx, wf);
        sm += wf;
    }
    aggout[(size_t)row * NFILT + lane]      = mx;
    aggout[(size_t)row * NFILT + 64 + lane] = sm * (1.0f / 39.0f);
}

// ---------------- K3: out = [x | max | mean] @ W_out + b_out --------------
// 32-row tiles, 512 threads (col c = tid&127, row-group rg = tid>>7, 8 rows).
// In-place over d_out: agg rows staged to LDS before overwrite.
__global__ __launch_bounds__(512) void k3_out(
    const float* __restrict__ x, const float* __restrict__ agg,
    const float* __restrict__ Wo, const float* __restrict__ bo,
    float* __restrict__ out)
{
    __shared__ float xa[32 * FIN];    // 8 KB
    __shared__ float ga[32 * NFILT];  // 16 KB
    int tid = threadIdx.x;
    int r0  = blockIdx.x * 32;
    for (int idx = tid; idx < 32 * FIN / 4; idx += 512)
        reinterpret_cast<float4*>(xa)[idx] =
            reinterpret_cast<const float4*>(x + (size_t)r0 * FIN)[idx];
    for (int idx = tid; idx < 32 * NFILT / 4; idx += 512)
        reinterpret_cast<float4*>(ga)[idx] =
            reinterpret_cast<const float4*>(agg + (size_t)r0 * NFILT)[idx];
    __syncthreads();

    int c = tid & 127, rg = tid >> 7;
    float acc[8];
    float bb = bo[c];
    #pragma unroll
    for (int r = 0; r < 8; ++r) acc[r] = bb;

    #pragma unroll 4
    for (int k = 0; k < FIN; k += 4) {
        float w0 = Wo[(k + 0) * NFILT + c];
        float w1 = Wo[(k + 1) * NFILT + c];
        float w2 = Wo[(k + 2) * NFILT + c];
        float w3 = Wo[(k + 3) * NFILT + c];
        #pragma unroll
        for (int r = 0; r < 8; ++r) {
            float4 xv = *reinterpret_cast<const float4*>(&xa[(rg * 8 + r) * FIN + k]);
            acc[r] = fmaf(xv.x, w0, fmaf(xv.y, w1, fmaf(xv.z, w2, fmaf(xv.w, w3, acc[r]))));
        }
    }
    #pragma unroll 4
    for (int k = 0; k < NFILT; k += 4) {
        float w0 = Wo[(FIN + k + 0) * NFILT + c];
        float w1 = Wo[(FIN + k + 1) * NFILT + c];
        float w2 = Wo[(FIN + k + 2) * NFILT + c];
        float w3 = Wo[(FIN + k + 3) * NFILT + c];
        #pragma unroll
        for (int r = 0; r < 8; ++r) {
            float4 gv = *reinterpret_cast<const float4*>(&ga[(rg * 8 + r) * NFILT + k]);
            acc[r] = fmaf(gv.x, w0, fmaf(gv.y, w1, fmaf(gv.z, w2, fmaf(gv.w, w3, acc[r]))));
        }
    }
    #pragma unroll
    for (int r = 0; r < 8; ++r)
        out[(size_t)(r0 + rg * 8 + r) * NFILT + c] = acc[r];
}

extern "C" void kernel_launch(void* const* d_in, const int* in_sizes, int n_in,
                              void* d_out, int out_size, void* d_ws, size_t ws_size,
                              hipStream_t stream)
{
    const float* x  = (const float*)d_in[0];
    const float* Wf = (const float*)d_in[1];
    const float* bf = (const float*)d_in[2];
    const float* Ws = (const float*)d_in[3];
    const float* bs = (const float*)d_in[4];
    const float* Wo = (const float*)d_in[5];
    const float* bo = (const float*)d_in[6];
    float* out = (float*)d_out;

    float*  feat   = (float*)d_ws;                                        // 4 MB
    float4* coords = (float4*)((char*)d_ws + (size_t)ROWS * NPROP * 4);   // 256 KB

    k1_proj<<<ROWS / 4,  256, 0, stream>>>(x, Wf, bf, Ws, bs, feat, coords);
    k2_knn <<<ROWS / 16, 1024, 0, stream>>>(coords, feat, out);
    k3_out <<<ROWS / 32, 512, 0, stream>>>(x, out, Wo, bo, out);
}